// Round 17
// baseline (208.747 us; speedup 1.0000x reference)
//
#include <hip/hip_runtime.h>
#include <hip/hip_fp16.h>
#include <math.h>

#define F 64
#define OUTF 32
#define PAD 64          // padded CSR width; in-degree is Poisson(10), max ~30-35
#define NEG_SLOPE 0.2f
#define GBCAP 6144      // per-bucket capacity (mean 5120, +14 sigma)

typedef _Float16 half8v __attribute__((ext_vector_type(8)));
typedef float    f32x4  __attribute__((ext_vector_type(4)));

__device__ __forceinline__ float leaky(float v) {
    return (v > 0.f) ? v : NEG_SLOPE * v;
}
__device__ __forceinline__ int rlanei(int v, int l) {
    return __builtin_amdgcn_readlane(v, l);
}
__device__ __forceinline__ float rlanef(float v, int l) {
    return __uint_as_float(__builtin_amdgcn_readlane(__float_as_uint(v), l));
}

// ---------------- MFMA transform core (layer-1 from global fp32 x) ----------------
// 16x16x32_f16 fragments. A/B: 16-dim = lane&15, k = (lane>>4)*8+j.
// C/D: col = lane&15, row = (lane>>4)*4 + reg  [m89-verified mapping].
template<typename TIN, int NC, bool FINAL>
__device__ __forceinline__ void mm_body(
    int tb, const TIN* __restrict__ in, const float* __restrict__ W,
    const float* __restrict__ a_s, const float* __restrict__ a_d,
    const float* __restrict__ bias,
    __half* __restrict__ h_out, float* __restrict__ f_out,
    float* __restrict__ As, float* __restrict__ Ad, int n)
{
    constexpr int NCT = NC / 16;
    int wv = threadIdx.x >> 6, l = threadIdx.x & 63;
    int g = l >> 4, c = l & 15;

    half8v bf[2][NCT];
    #pragma unroll
    for (int kt = 0; kt < 2; ++kt) {
        #pragma unroll
        for (int ct = 0; ct < NCT; ++ct) {
            half8v b;
            #pragma unroll
            for (int j = 0; j < 8; ++j)
                b[j] = (_Float16)W[(kt * 32 + g * 8 + j) * NC + ct * 16 + c];
            bf[kt][ct] = b;
        }
    }
    float asv[NCT], adv[NCT], bsv[NCT];
    #pragma unroll
    for (int ct = 0; ct < NCT; ++ct) {
        if constexpr (!FINAL) { asv[ct] = a_s[ct * 16 + c]; adv[ct] = a_d[ct * 16 + c]; }
        else                  { bsv[ct] = bias[ct * 16 + c]; }
    }

    int tile0 = tb * 256 + wv * 64;
    #pragma unroll
    for (int t = 0; t < 4; ++t) {
        int br = tile0 + t * 16;
        if (br >= n) break;                               // wave-uniform
        int lrow = min(br + c, n - 1);                    // A row = lane&15
        half8v a0, a1;
        if constexpr (sizeof(TIN) == 4) {                 // fp32 input (layer 1)
            const float4* p0 = (const float4*)((const float*)in + (size_t)lrow * NC + g * 8);
            const float4* p1 = (const float4*)((const float*)in + (size_t)lrow * NC + 32 + g * 8);
            float4 q0 = p0[0], q1 = p0[1], q2 = p1[0], q3 = p1[1];
            a0[0]=(_Float16)q0.x; a0[1]=(_Float16)q0.y; a0[2]=(_Float16)q0.z; a0[3]=(_Float16)q0.w;
            a0[4]=(_Float16)q1.x; a0[5]=(_Float16)q1.y; a0[6]=(_Float16)q1.z; a0[7]=(_Float16)q1.w;
            a1[0]=(_Float16)q2.x; a1[1]=(_Float16)q2.y; a1[2]=(_Float16)q2.z; a1[3]=(_Float16)q2.w;
            a1[4]=(_Float16)q3.x; a1[5]=(_Float16)q3.y; a1[6]=(_Float16)q3.z; a1[7]=(_Float16)q3.w;
        } else {
            a0 = *(const half8v*)((const __half*)in + (size_t)lrow * F + g * 8);
            a1 = *(const half8v*)((const __half*)in + (size_t)lrow * F + 32 + g * 8);
        }
        f32x4 acc[NCT];
        #pragma unroll
        for (int ct = 0; ct < NCT; ++ct) acc[ct] = (f32x4){0.f, 0.f, 0.f, 0.f};
        #pragma unroll
        for (int ct = 0; ct < NCT; ++ct) {
            acc[ct] = __builtin_amdgcn_mfma_f32_16x16x32_f16(a0, bf[0][ct], acc[ct], 0, 0, 0);
            acc[ct] = __builtin_amdgcn_mfma_f32_16x16x32_f16(a1, bf[1][ct], acc[ct], 0, 0, 0);
        }

        if constexpr (!FINAL) {
            #pragma unroll
            for (int ct = 0; ct < NCT; ++ct)
                #pragma unroll
                for (int r = 0; r < 4; ++r) {
                    int rr = br + g * 4 + r;
                    if (rr < n) h_out[(size_t)rr * NC + ct * 16 + c] = __float2half(acc[ct][r]);
                }
            float ps[4], pd[4];
            #pragma unroll
            for (int r = 0; r < 4; ++r) {
                float s = 0.f, d2 = 0.f;
                #pragma unroll
                for (int ct = 0; ct < NCT; ++ct) {
                    s  = fmaf(acc[ct][r], asv[ct], s);
                    d2 = fmaf(acc[ct][r], adv[ct], d2);
                }
                ps[r] = s; pd[r] = d2;
            }
            #pragma unroll
            for (int off = 1; off < 16; off <<= 1) {
                #pragma unroll
                for (int r = 0; r < 4; ++r) {
                    ps[r] += __shfl_xor(ps[r], off, 64);
                    pd[r] += __shfl_xor(pd[r], off, 64);
                }
            }
            if (c == 0) {
                #pragma unroll
                for (int r = 0; r < 4; ++r) {
                    int rr = br + g * 4 + r;
                    if (rr < n) { As[rr] = ps[r]; Ad[rr] = pd[r]; }
                }
            }
        } else {
            #pragma unroll
            for (int ct = 0; ct < NCT; ++ct)
                #pragma unroll
                for (int r = 0; r < 4; ++r) {
                    int rr = br + g * 4 + r;
                    if (rr < n) f_out[(size_t)rr * NC + ct * 16 + c] = acc[ct][r] + bsv[ct];
                }
        }
    }
}

// ---------------- zero gcount ----------------
__global__ __launch_bounds__(256) void zero256(int* __restrict__ p) {
    p[threadIdx.x] = 0;
}

// ---------------- pass 1: bucket partition of edges, fused with layer-1 MFMA transform ----------------
__global__ __launch_bounds__(256, 4) void build_or_transform(
    const int* __restrict__ src, const int* __restrict__ dst, int E,
    int* __restrict__ gcount, int2* __restrict__ bucketed,
    const float* __restrict__ x, const float* __restrict__ W,
    const float* __restrict__ a_s, const float* __restrict__ a_d,
    __half* __restrict__ h, float* __restrict__ As, float* __restrict__ Ad,
    int n, int GP)
{
    __shared__ int lcnt[256];
    __shared__ int lbase[256];
    if ((int)blockIdx.x < GP) {
        int tid = threadIdx.x;
        lcnt[tid] = 0;
        __syncthreads();
        int base = blockIdx.x * 4096;
        int dd[16], ss[16], bb[16];
        #pragma unroll
        for (int i = 0; i < 16; ++i) {
            int e = base + i * 256 + tid;
            if (e < E) {
                dd[i] = dst[e]; ss[i] = src[e]; bb[i] = dd[i] >> 9;
                atomicAdd(&lcnt[bb[i]], 1);
            } else bb[i] = -1;
        }
        __syncthreads();
        lbase[tid] = (lcnt[tid] > 0) ? atomicAdd(&gcount[tid], lcnt[tid]) : 0;
        __syncthreads();
        lcnt[tid] = 0;
        __syncthreads();
        #pragma unroll
        for (int i = 0; i < 16; ++i) {
            if (bb[i] >= 0) {
                int pos = lbase[bb[i]] + atomicAdd(&lcnt[bb[i]], 1);
                if (pos < GBCAP)
                    bucketed[(size_t)bb[i] * GBCAP + pos] = make_int2(dd[i], ss[i]);
            }
        }
    } else {
        mm_body<float, F, false>(blockIdx.x - GP, x, W, a_s, a_d, nullptr,
                                 h, nullptr, As, Ad, n);
    }
}

// ---------------- pass 2: bucket -> padded CSR ----------------
__global__ __launch_bounds__(256) void bucket_to_csr(
    const int* __restrict__ gcount, const int2* __restrict__ bucketed,
    int* __restrict__ cnt, int* __restrict__ csr, int n)
{
    __shared__ int lcnt[512], lofs[512], lcur[512];
    __shared__ int lbin[GBCAP];
    int bkt = blockIdx.x, tid = threadIdx.x;
    int d0 = bkt << 9;
    int nent = min(gcount[bkt], GBCAP);
    lcnt[tid] = 0; lcnt[tid + 256] = 0;
    __syncthreads();
    const int2* bb = bucketed + (size_t)bkt * GBCAP;
    for (int i = tid; i < nent; i += 256) atomicAdd(&lcnt[bb[i].x - d0], 1);
    __syncthreads();
    if (tid < 64) {
        int run = 0;
        for (int c = 0; c < 8; ++c) {
            int v = lcnt[c * 64 + tid];
            int inc = v;
            #pragma unroll
            for (int o = 1; o < 64; o <<= 1) {
                int t = __shfl_up(inc, o, 64);
                if (tid >= o) inc += t;
            }
            lofs[c * 64 + tid] = run + inc - v;
            run += __shfl(inc, 63, 64);
        }
    }
    __syncthreads();
    lcur[tid] = lofs[tid]; lcur[tid + 256] = lofs[tid + 256];
    __syncthreads();
    for (int i = tid; i < nent; i += 256) {
        int2 p = bb[i];
        int ld = p.x - d0;
        int pos = atomicAdd(&lcur[ld], 1);
        if (pos - lofs[ld] < PAD) lbin[pos] = p.y;
    }
    __syncthreads();
    for (int t = tid; t < 512 * PAD; t += 256) {
        int ld = t >> 6, i = t & 63;
        int d = d0 + ld;
        if (d >= n) continue;
        int c = min(lcnt[ld], PAD);
        csr[(size_t)d * PAD + i] = (i < c) ? lbin[lofs[ld] + i] : 0;
    }
    for (int t = tid; t < 512; t += 256) {
        int d = d0 + t;
        if (d < n) cnt[d] = min(lcnt[t], PAD);
    }
}

// ---------------- fused: aggregate 16 dsts/wave -> y in wave-private LDS -> MFMA @ W ----------------
// Agg math byte-identical to round-15 agg_slim. LDS tile [16][72] (2-way aliasing, free).
// RACE FIX (round 16): alphas are READ for arbitrary src nodes and WRITTEN for own
// rows -> must use separate in/out buffers (aS0/aD0 <-> aS1/aD1 ping-pong), like h.
template<int NC, bool FINAL>
__global__ __launch_bounds__(256) void agg_mm(
    const int* __restrict__ cnt, const int* __restrict__ csr,
    const float* __restrict__ a_s, const float* __restrict__ a_d,
    const __half* __restrict__ h, const float* __restrict__ bias,
    const float* __restrict__ Wn, const float* __restrict__ asn,
    const float* __restrict__ adn, const float* __restrict__ bln,
    __half* __restrict__ h_out, float* __restrict__ f_out,
    float* __restrict__ As_out, float* __restrict__ Ad_out, int n)
{
    constexpr int NCT = NC / 16;
    __shared__ __half y_lds[4][16][72];
    int wave = threadIdx.x >> 6, lane = threadIdx.x & 63;
    int base = blockIdx.x * 64 + wave * 16;
    if (base >= n) return;                               // wave-uniform

    if (base + 16 > n) {                                 // tail: zero-fill garbage rows
        #pragma unroll
        for (int r = 0; r < 16; ++r) y_lds[wave][r][lane] = __float2half(0.f);
    }

    // ---- aggregate phase: 8 sequential ILP-2 pairs ----
    for (int p = 0; p < 8; ++p) {
        int dA = base + p * 2;
        if (dA >= n) break;                              // wave-uniform
        bool hasB = (dA + 1 < n);
        int dB = hasB ? dA + 1 : dA;

        int degA = min(cnt[dA], PAD);
        int degB = min(cnt[dB], PAD);
        int sA = (lane < degA) ? csr[(size_t)dA * PAD + lane] : dA;
        int sB = (lane < degB) ? csr[(size_t)dB * PAD + lane] : dB;

        float hsA = __half2float(h[(size_t)dA * F + lane]);
        float hsB = __half2float(h[(size_t)dB * F + lane]);
        __half vA[16], vB[16];
        #pragma unroll
        for (int u = 0; u < 16; ++u) {
            vA[u] = h[(size_t)rlanei(sA, u) * F + lane];
            vB[u] = h[(size_t)rlanei(sB, u) * F + lane];
        }
        float asA_l = a_s[sA];
        float asB_l = a_s[sB];
        float adA = a_d[dA], adB = a_d[dB];
        float asA_d = a_s[dA], asB_d = a_s[dB];

        float wsfA = __expf(leaky(asA_d + adA));
        float wsfB = __expf(leaky(asB_d + adB));
        float wA = (lane < degA) ? __expf(leaky(asA_l + adA)) : 0.f;
        float wB = (lane < degB) ? __expf(leaky(asB_l + adB)) : 0.f;

        float accA = wsfA * hsA;
        float accB = wsfB * hsB;
        float wsumA = 0.f, wsumB = 0.f;
        int rounds = (min(max(degA, degB), 16) + 3) >> 2;

#define AGG_CHUNK(c)                                                          \
        {                                                                     \
            float a0 = rlanef(wA, 4*(c)+0), a1 = rlanef(wA, 4*(c)+1);         \
            float a2 = rlanef(wA, 4*(c)+2), a3 = rlanef(wA, 4*(c)+3);         \
            float b0 = rlanef(wB, 4*(c)+0), b1 = rlanef(wB, 4*(c)+1);         \
            float b2 = rlanef(wB, 4*(c)+2), b3 = rlanef(wB, 4*(c)+3);         \
            accA = fmaf(a0, __half2float(vA[4*(c)+0]), accA);                 \
            accA = fmaf(a1, __half2float(vA[4*(c)+1]), accA);                 \
            accA = fmaf(a2, __half2float(vA[4*(c)+2]), accA);                 \
            accA = fmaf(a3, __half2float(vA[4*(c)+3]), accA);                 \
            accB = fmaf(b0, __half2float(vB[4*(c)+0]), accB);                 \
            accB = fmaf(b1, __half2float(vB[4*(c)+1]), accB);                 \
            accB = fmaf(b2, __half2float(vB[4*(c)+2]), accB);                 \
            accB = fmaf(b3, __half2float(vB[4*(c)+3]), accB);                 \
            wsumA += (a0 + a1) + (a2 + a3);                                   \
            wsumB += (b0 + b1) + (b2 + b3);                                   \
        }
        switch (rounds) {
            case 4: AGG_CHUNK(3); [[fallthrough]];
            case 3: AGG_CHUNK(2); [[fallthrough]];
            case 2: AGG_CHUNK(1); [[fallthrough]];
            case 1: AGG_CHUNK(0); break;
            default: break;
        }
#undef AGG_CHUNK

        for (int b = 16; b < degA; b += 16) {
            #pragma unroll
            for (int u = 0; u < 16; ++u) {
                int idx = b + u;
                float wj = rlanef(wA, idx);
                accA = fmaf(wj, __half2float(h[(size_t)rlanei(sA, idx) * F + lane]), accA);
                wsumA += wj;
            }
        }
        for (int b = 16; b < degB; b += 16) {
            #pragma unroll
            for (int u = 0; u < 16; ++u) {
                int idx = b + u;
                float wj = rlanef(wB, idx);
                accB = fmaf(wj, __half2float(h[(size_t)rlanei(sB, idx) * F + lane]), accB);
                wsumB += wj;
            }
        }
        float bv = bias[lane];
        float yA = fmaxf(accA / (wsumA + wsfA + 1e-16f) + bv, 0.f);
        float yB = fmaxf(accB / (wsumB + wsfB + 1e-16f) + bv, 0.f);
        y_lds[wave][p * 2][lane] = __float2half(yA);
        if (hasB) y_lds[wave][p * 2 + 1][lane] = __float2half(yB);
    }

    // ---- MFMA phase: this wave's 16 y-rows @ W (wave-private LDS, no barrier) ----
    int g = lane >> 4, c = lane & 15;
    half8v bf[2][NCT];
    #pragma unroll
    for (int kt = 0; kt < 2; ++kt) {
        #pragma unroll
        for (int ct = 0; ct < NCT; ++ct) {
            half8v b;
            #pragma unroll
            for (int j = 0; j < 8; ++j)
                b[j] = (_Float16)Wn[(kt * 32 + g * 8 + j) * NC + ct * 16 + c];
            bf[kt][ct] = b;
        }
    }
    half8v a0 = *(const half8v*)&y_lds[wave][c][g * 8];
    half8v a1 = *(const half8v*)&y_lds[wave][c][32 + g * 8];
    f32x4 acc[NCT];
    #pragma unroll
    for (int ct = 0; ct < NCT; ++ct) acc[ct] = (f32x4){0.f, 0.f, 0.f, 0.f};
    #pragma unroll
    for (int ct = 0; ct < NCT; ++ct) {
        acc[ct] = __builtin_amdgcn_mfma_f32_16x16x32_f16(a0, bf[0][ct], acc[ct], 0, 0, 0);
        acc[ct] = __builtin_amdgcn_mfma_f32_16x16x32_f16(a1, bf[1][ct], acc[ct], 0, 0, 0);
    }

    if constexpr (!FINAL) {
        float asv[NCT], adv[NCT];
        #pragma unroll
        for (int ct = 0; ct < NCT; ++ct) { asv[ct] = asn[ct * 16 + c]; adv[ct] = adn[ct * 16 + c]; }
        #pragma unroll
        for (int ct = 0; ct < NCT; ++ct)
            #pragma unroll
            for (int r = 0; r < 4; ++r) {
                int rr = base + g * 4 + r;
                if (rr < n) h_out[(size_t)rr * NC + ct * 16 + c] = __float2half(acc[ct][r]);
            }
        float ps[4], pd[4];
        #pragma unroll
        for (int r = 0; r < 4; ++r) {
            float s = 0.f, d2 = 0.f;
            #pragma unroll
            for (int ct = 0; ct < NCT; ++ct) {
                s  = fmaf(acc[ct][r], asv[ct], s);
                d2 = fmaf(acc[ct][r], adv[ct], d2);
            }
            ps[r] = s; pd[r] = d2;
        }
        #pragma unroll
        for (int off = 1; off < 16; off <<= 1) {
            #pragma unroll
            for (int r = 0; r < 4; ++r) {
                ps[r] += __shfl_xor(ps[r], off, 64);
                pd[r] += __shfl_xor(pd[r], off, 64);
            }
        }
        if (c == 0) {
            #pragma unroll
            for (int r = 0; r < 4; ++r) {
                int rr = base + g * 4 + r;
                if (rr < n) { As_out[rr] = ps[r]; Ad_out[rr] = pd[r]; }
            }
        }
    } else {
        float bsv[NCT];
        #pragma unroll
        for (int ct = 0; ct < NCT; ++ct) bsv[ct] = bln[ct * 16 + c];
        #pragma unroll
        for (int ct = 0; ct < NCT; ++ct)
            #pragma unroll
            for (int r = 0; r < 4; ++r) {
                int rr = base + g * 4 + r;
                if (rr < n) f_out[(size_t)rr * NC + ct * 16 + c] = acc[ct][r] + bsv[ct];
            }
    }
}

extern "C" void kernel_launch(void* const* d_in, const int* in_sizes, int n_in,
                              void* d_out, int out_size, void* d_ws, size_t ws_size,
                              hipStream_t stream)
{
    const float* x  = (const float*)d_in[0];
    const int*   ei = (const int*)d_in[1];
    int N = in_sizes[0] / F;
    int E = in_sizes[1] / 2;
    const int* src = ei;
    const int* dst = ei + E;

    const float* W1  = (const float*)d_in[2];
    const float* as1 = (const float*)d_in[3];
    const float* ad1 = (const float*)d_in[4];
    const float* b1  = (const float*)d_in[5];
    const float* W2  = (const float*)d_in[6];
    const float* as2 = (const float*)d_in[7];
    const float* ad2 = (const float*)d_in[8];
    const float* b2  = (const float*)d_in[9];
    const float* W3  = (const float*)d_in[10];
    const float* as3 = (const float*)d_in[11];
    const float* ad3 = (const float*)d_in[12];
    const float* b3  = (const float*)d_in[13];
    const float* Wl  = (const float*)d_in[14];
    const float* bl  = (const float*)d_in[15];

    int NBUK = (N + 511) >> 9;            // 196 for N=100000

    float* ws = (float*)d_ws;
    size_t off = 0;
    __half* hA = (__half*)(ws + off); off += (size_t)N * F / 2;
    __half* hB = (__half*)(ws + off); off += (size_t)N * F / 2;
    float* aS0 = ws + off; off += N;
    float* aD0 = ws + off; off += N;
    float* aS1 = ws + off; off += N;
    float* aD1 = ws + off; off += N;
    int* cnt = (int*)(ws + off); off += N;
    int* gcount = (int*)(ws + off); off += 256;
    int* csr = (int*)(ws + off); off += (size_t)N * PAD;
    int2* bucketed = (int2*)(ws + off); off += (size_t)NBUK * GBCAP * 2;

    dim3 blk(256);
    int TB  = (N + 255) / 256;
    int NB64 = (N + 63) / 64;
    int GP  = (E + 4095) / 4096;

    // CSR build (bucket partition) + layer-1 MFMA transform, overlapped
    zero256<<<1, blk, 0, stream>>>(gcount);
    build_or_transform<<<GP + TB, blk, 0, stream>>>(src, dst, E, gcount, bucketed,
                                                    x, W1, as1, ad1, hA, aS0, aD0, N, GP);
    bucket_to_csr<<<NBUK, blk, 0, stream>>>(gcount, bucketed, cnt, csr, N);

    // layer 1 agg + transform2 (fused): read aS0/aD0, write aS1/aD1
    agg_mm<F, false><<<NB64, blk, 0, stream>>>(cnt, csr, aS0, aD0, hA, b1,
                                               W2, as2, ad2, nullptr,
                                               hB, nullptr, aS1, aD1, N);
    // layer 2 agg + transform3 (fused): read aS1/aD1, write aS0/aD0
    agg_mm<F, false><<<NB64, blk, 0, stream>>>(cnt, csr, aS1, aD1, hB, b2,
                                               W3, as3, ad3, nullptr,
                                               hA, nullptr, aS0, aD0, N);
    // layer 3 agg + final linear (fused): read aS0/aD0, write nothing
    agg_mm<OUTF, true><<<NB64, blk, 0, stream>>>(cnt, csr, aS0, aD0, hA, b3,
                                                 Wl, nullptr, nullptr, bl,
                                                 nullptr, (float*)d_out, nullptr, nullptr, N);
}

// Round 18
// 165.405 us; speedup vs baseline: 1.2620x; 1.2620x over previous
//
#include <hip/hip_runtime.h>
#include <hip/hip_fp16.h>
#include <math.h>

#define F 64
#define OUTF 32
#define PAD 64          // padded CSR width; in-degree is Poisson(10), max ~30-35
#define NEG_SLOPE 0.2f
#define GBCAP 3328      // per-bucket capacity (256-dst buckets: mean 2560, +15 sigma)

typedef _Float16 half8v __attribute__((ext_vector_type(8)));
typedef float    f32x4  __attribute__((ext_vector_type(4)));

__device__ __forceinline__ float leaky(float v) {
    return (v > 0.f) ? v : NEG_SLOPE * v;
}
__device__ __forceinline__ int rlanei(int v, int l) {
    return __builtin_amdgcn_readlane(v, l);
}
__device__ __forceinline__ float rlanef(float v, int l) {
    return __uint_as_float(__builtin_amdgcn_readlane(__float_as_uint(v), l));
}

// ---------------- MFMA transform core ----------------
// 16x16x32_f16 fragments. A/B: 16-dim = lane&15, k = (lane>>4)*8+j.
// C/D: col = lane&15, row = (lane>>4)*4 + reg  [m89-verified mapping].
template<typename TIN, int NC, bool FINAL>
__device__ __forceinline__ void mm_body(
    int tb, const TIN* __restrict__ in, const float* __restrict__ W,
    const float* __restrict__ a_s, const float* __restrict__ a_d,
    const float* __restrict__ bias,
    __half* __restrict__ h_out, float* __restrict__ f_out,
    float* __restrict__ As, float* __restrict__ Ad, int n)
{
    constexpr int NCT = NC / 16;
    int wv = threadIdx.x >> 6, l = threadIdx.x & 63;
    int g = l >> 4, c = l & 15;

    half8v bf[2][NCT];
    #pragma unroll
    for (int kt = 0; kt < 2; ++kt) {
        #pragma unroll
        for (int ct = 0; ct < NCT; ++ct) {
            half8v b;
            #pragma unroll
            for (int j = 0; j < 8; ++j)
                b[j] = (_Float16)W[(kt * 32 + g * 8 + j) * NC + ct * 16 + c];
            bf[kt][ct] = b;
        }
    }
    float asv[NCT], adv[NCT], bsv[NCT];
    #pragma unroll
    for (int ct = 0; ct < NCT; ++ct) {
        if constexpr (!FINAL) { asv[ct] = a_s[ct * 16 + c]; adv[ct] = a_d[ct * 16 + c]; }
        else                  { bsv[ct] = bias[ct * 16 + c]; }
    }

    int tile0 = tb * 256 + wv * 64;
    #pragma unroll
    for (int t = 0; t < 4; ++t) {
        int br = tile0 + t * 16;
        if (br >= n) break;                               // wave-uniform
        int lrow = min(br + c, n - 1);                    // A row = lane&15
        half8v a0, a1;
        if constexpr (sizeof(TIN) == 4) {                 // fp32 input (layer 1)
            const float4* p0 = (const float4*)((const float*)in + (size_t)lrow * NC + g * 8);
            const float4* p1 = (const float4*)((const float*)in + (size_t)lrow * NC + 32 + g * 8);
            float4 q0 = p0[0], q1 = p0[1], q2 = p1[0], q3 = p1[1];
            a0[0]=(_Float16)q0.x; a0[1]=(_Float16)q0.y; a0[2]=(_Float16)q0.z; a0[3]=(_Float16)q0.w;
            a0[4]=(_Float16)q1.x; a0[5]=(_Float16)q1.y; a0[6]=(_Float16)q1.z; a0[7]=(_Float16)q1.w;
            a1[0]=(_Float16)q2.x; a1[1]=(_Float16)q2.y; a1[2]=(_Float16)q2.z; a1[3]=(_Float16)q2.w;
            a1[4]=(_Float16)q3.x; a1[5]=(_Float16)q3.y; a1[6]=(_Float16)q3.z; a1[7]=(_Float16)q3.w;
        } else {
            a0 = *(const half8v*)((const __half*)in + (size_t)lrow * F + g * 8);
            a1 = *(const half8v*)((const __half*)in + (size_t)lrow * F + 32 + g * 8);
        }
        f32x4 acc[NCT];
        #pragma unroll
        for (int ct = 0; ct < NCT; ++ct) acc[ct] = (f32x4){0.f, 0.f, 0.f, 0.f};
        #pragma unroll
        for (int ct = 0; ct < NCT; ++ct) {
            acc[ct] = __builtin_amdgcn_mfma_f32_16x16x32_f16(a0, bf[0][ct], acc[ct], 0, 0, 0);
            acc[ct] = __builtin_amdgcn_mfma_f32_16x16x32_f16(a1, bf[1][ct], acc[ct], 0, 0, 0);
        }

        if constexpr (!FINAL) {
            #pragma unroll
            for (int ct = 0; ct < NCT; ++ct)
                #pragma unroll
                for (int r = 0; r < 4; ++r) {
                    int rr = br + g * 4 + r;
                    if (rr < n) h_out[(size_t)rr * NC + ct * 16 + c] = __float2half(acc[ct][r]);
                }
            float ps[4], pd[4];
            #pragma unroll
            for (int r = 0; r < 4; ++r) {
                float s = 0.f, d2 = 0.f;
                #pragma unroll
                for (int ct = 0; ct < NCT; ++ct) {
                    s  = fmaf(acc[ct][r], asv[ct], s);
                    d2 = fmaf(acc[ct][r], adv[ct], d2);
                }
                ps[r] = s; pd[r] = d2;
            }
            #pragma unroll
            for (int off = 1; off < 16; off <<= 1) {
                #pragma unroll
                for (int r = 0; r < 4; ++r) {
                    ps[r] += __shfl_xor(ps[r], off, 64);
                    pd[r] += __shfl_xor(pd[r], off, 64);
                }
            }
            if (c == 0) {
                #pragma unroll
                for (int r = 0; r < 4; ++r) {
                    int rr = br + g * 4 + r;
                    if (rr < n) { As[rr] = ps[r]; Ad[rr] = pd[r]; }
                }
            }
        } else {
            #pragma unroll
            for (int ct = 0; ct < NCT; ++ct)
                #pragma unroll
                for (int r = 0; r < 4; ++r) {
                    int rr = br + g * 4 + r;
                    if (rr < n) f_out[(size_t)rr * NC + ct * 16 + c] = acc[ct][r] + bsv[ct];
                }
        }
    }
}

template<typename TIN, int NC, bool FINAL>
__global__ __launch_bounds__(256, 4) void mm_mfma(
    const TIN* __restrict__ in, const float* __restrict__ W,
    const float* __restrict__ a_s, const float* __restrict__ a_d,
    const float* __restrict__ bias,
    __half* __restrict__ h_out, float* __restrict__ f_out,
    float* __restrict__ As, float* __restrict__ Ad, int n)
{
    mm_body<TIN, NC, FINAL>(blockIdx.x, in, W, a_s, a_d, bias, h_out, f_out, As, Ad, n);
}

// ---------------- zero gcount (512 buckets) ----------------
__global__ __launch_bounds__(256) void zero512(int* __restrict__ p) {
    p[threadIdx.x] = 0;
    p[threadIdx.x + 256] = 0;
}

// ---------------- pass 1: bucket partition (256-dst buckets), fused with layer-1 transform ----------------
__global__ __launch_bounds__(256, 4) void build_or_transform(
    const int* __restrict__ src, const int* __restrict__ dst, int E,
    int* __restrict__ gcount, int2* __restrict__ bucketed,
    const float* __restrict__ x, const float* __restrict__ W,
    const float* __restrict__ a_s, const float* __restrict__ a_d,
    __half* __restrict__ h, float* __restrict__ As, float* __restrict__ Ad,
    int n, int GP)
{
    __shared__ int lcnt[512];
    __shared__ int lbase[512];
    if ((int)blockIdx.x < GP) {
        int tid = threadIdx.x;
        lcnt[tid] = 0; lcnt[tid + 256] = 0;
        __syncthreads();
        int base = blockIdx.x * 4096;
        int dd[16], ss[16], bb[16];
        #pragma unroll
        for (int i = 0; i < 16; ++i) {
            int e = base + i * 256 + tid;
            if (e < E) {
                dd[i] = dst[e]; ss[i] = src[e]; bb[i] = dd[i] >> 8;
                atomicAdd(&lcnt[bb[i]], 1);
            } else bb[i] = -1;
        }
        __syncthreads();
        lbase[tid] = (lcnt[tid] > 0) ? atomicAdd(&gcount[tid], lcnt[tid]) : 0;
        lbase[tid + 256] = (lcnt[tid + 256] > 0) ? atomicAdd(&gcount[tid + 256], lcnt[tid + 256]) : 0;
        __syncthreads();
        lcnt[tid] = 0; lcnt[tid + 256] = 0;
        __syncthreads();
        #pragma unroll
        for (int i = 0; i < 16; ++i) {
            if (bb[i] >= 0) {
                int pos = lbase[bb[i]] + atomicAdd(&lcnt[bb[i]], 1);
                if (pos < GBCAP)
                    bucketed[(size_t)bb[i] * GBCAP + pos] = make_int2(dd[i], ss[i]);
            }
        }
    } else {
        mm_body<float, F, false>(blockIdx.x - GP, x, W, a_s, a_d, nullptr,
                                 h, nullptr, As, Ad, n);
    }
}

// ---------------- pass 2: bucket -> padded CSR (write only used slots) ----------------
__global__ __launch_bounds__(256) void bucket_to_csr(
    const int* __restrict__ gcount, const int2* __restrict__ bucketed,
    int* __restrict__ cnt, int* __restrict__ csr, int n)
{
    __shared__ int lcnt[256], lofs[256], lcur[256];
    __shared__ int lbin[GBCAP];
    int bkt = blockIdx.x, tid = threadIdx.x;
    int d0 = bkt << 8;
    int nent = min(gcount[bkt], GBCAP);
    lcnt[tid] = 0;
    __syncthreads();
    const int2* bb = bucketed + (size_t)bkt * GBCAP;
    for (int i = tid; i < nent; i += 256) atomicAdd(&lcnt[bb[i].x - d0], 1);
    __syncthreads();
    if (tid < 64) {                       // exclusive scan of lcnt -> lofs (wave 0)
        int run = 0;
        for (int c = 0; c < 4; ++c) {
            int v = lcnt[c * 64 + tid];
            int inc = v;
            #pragma unroll
            for (int o = 1; o < 64; o <<= 1) {
                int t = __shfl_up(inc, o, 64);
                if (tid >= o) inc += t;
            }
            lofs[c * 64 + tid] = run + inc - v;
            run += __shfl(inc, 63, 64);
        }
    }
    __syncthreads();
    lcur[tid] = lofs[tid];
    __syncthreads();
    for (int i = tid; i < nent; i += 256) {
        int2 p = bb[i];
        int ld = p.x - d0;
        int pos = atomicAdd(&lcur[ld], 1);
        if (pos - lofs[ld] < PAD) lbin[pos] = p.y;
    }
    __syncthreads();
    // only write the slots agg will read (lane < deg); unused slots stay garbage
    for (int t = tid; t < 256 * PAD; t += 256) {
        int ld = t >> 6, i = t & 63;
        int d = d0 + ld;
        if (d >= n) continue;
        int c = min(lcnt[ld], PAD);
        if (i < c) csr[(size_t)d * PAD + i] = lbin[lofs[ld] + i];
    }
    if (d0 + tid < n) cnt[d0 + tid] = min(lcnt[tid], PAD);
}

// ---------------- slim aggregation (2 dsts/wave, readlane broadcasts, zero DS) ----------------
// No max-subtraction (|logits| <~ 12 << 88; shift-invariant).
// wsum via VALU tree of the already-materialized readlane w values. Gather loop
// bounded at wave-uniform ceil(min(maxdeg,16)/4) via fall-through switch.
__global__ __launch_bounds__(256) void agg_slim(
    const int* __restrict__ cnt, const int* __restrict__ csr,
    const float* __restrict__ a_s, const float* __restrict__ a_d,
    const __half* __restrict__ h, const float* __restrict__ bias,
    __half* __restrict__ y_out, int n)
{
    int wave = threadIdx.x >> 6, lane = threadIdx.x & 63;
    int dA = blockIdx.x * 8 + wave * 2;
    if (dA >= n) return;
    bool hasB = (dA + 1 < n);
    int dB = hasB ? dA + 1 : dA;

    int degA = min(cnt[dA], PAD);
    int degB = min(cnt[dB], PAD);

    int sA = (lane < degA) ? csr[(size_t)dA * PAD + lane] : dA;
    int sB = (lane < degB) ? csr[(size_t)dB * PAD + lane] : dB;

    // issue all gathers up front; weight math overlaps the latency
    float hsA = __half2float(h[(size_t)dA * F + lane]);
    float hsB = __half2float(h[(size_t)dB * F + lane]);
    __half vA[16], vB[16];
    #pragma unroll
    for (int u = 0; u < 16; ++u) {
        vA[u] = h[(size_t)rlanei(sA, u) * F + lane];
        vB[u] = h[(size_t)rlanei(sB, u) * F + lane];
    }
    float asA_l = a_s[sA];
    float asB_l = a_s[sB];

    float adA = a_d[dA], adB = a_d[dB];          // wave-uniform scalar loads
    float asA_d = a_s[dA], asB_d = a_s[dB];

    float wsfA = __expf(leaky(asA_d + adA));
    float wsfB = __expf(leaky(asB_d + adB));
    float wA = (lane < degA) ? __expf(leaky(asA_l + adA)) : 0.f;
    float wB = (lane < degB) ? __expf(leaky(asB_l + adB)) : 0.f;

    float accA = wsfA * hsA;
    float accB = wsfB * hsB;
    float wsumA = 0.f, wsumB = 0.f;

    int rounds = (min(max(degA, degB), 16) + 3) >> 2;   // 0..4, wave-uniform

#define AGG_CHUNK(c)                                                          \
    {                                                                         \
        float a0 = rlanef(wA, 4*(c)+0), a1 = rlanef(wA, 4*(c)+1);             \
        float a2 = rlanef(wA, 4*(c)+2), a3 = rlanef(wA, 4*(c)+3);             \
        float b0 = rlanef(wB, 4*(c)+0), b1 = rlanef(wB, 4*(c)+1);             \
        float b2 = rlanef(wB, 4*(c)+2), b3 = rlanef(wB, 4*(c)+3);             \
        accA = fmaf(a0, __half2float(vA[4*(c)+0]), accA);                     \
        accA = fmaf(a1, __half2float(vA[4*(c)+1]), accA);                     \
        accA = fmaf(a2, __half2float(vA[4*(c)+2]), accA);                     \
        accA = fmaf(a3, __half2float(vA[4*(c)+3]), accA);                     \
        accB = fmaf(b0, __half2float(vB[4*(c)+0]), accB);                     \
        accB = fmaf(b1, __half2float(vB[4*(c)+1]), accB);                     \
        accB = fmaf(b2, __half2float(vB[4*(c)+2]), accB);                     \
        accB = fmaf(b3, __half2float(vB[4*(c)+3]), accB);                     \
        wsumA += (a0 + a1) + (a2 + a3);                                       \
        wsumB += (b0 + b1) + (b2 + b3);                                       \
    }

    switch (rounds) {
        case 4: AGG_CHUNK(3); [[fallthrough]];
        case 3: AGG_CHUNK(2); [[fallthrough]];
        case 2: AGG_CHUNK(1); [[fallthrough]];
        case 1: AGG_CHUNK(0); break;
        default: break;
    }
#undef AGG_CHUNK

    for (int b = 16; b < degA; b += 16) {        // rare tail (P(deg>16) ~ 2.6%)
        #pragma unroll
        for (int u = 0; u < 16; ++u) {
            int idx = b + u;
            float wj = rlanef(wA, idx);
            accA = fmaf(wj, __half2float(h[(size_t)rlanei(sA, idx) * F + lane]), accA);
            wsumA += wj;
        }
    }
    for (int b = 16; b < degB; b += 16) {
        #pragma unroll
        for (int u = 0; u < 16; ++u) {
            int idx = b + u;
            float wj = rlanef(wB, idx);
            accB = fmaf(wj, __half2float(h[(size_t)rlanei(sB, idx) * F + lane]), accB);
            wsumB += wj;
        }
    }
    float bv = bias[lane];
    float yA = fmaxf(accA / (wsumA + wsfA + 1e-16f) + bv, 0.f);
    float yB = fmaxf(accB / (wsumB + wsfB + 1e-16f) + bv, 0.f);
    y_out[(size_t)dA * F + lane] = __float2half(yA);
    if (hasB) y_out[(size_t)dB * F + lane] = __float2half(yB);
}

extern "C" void kernel_launch(void* const* d_in, const int* in_sizes, int n_in,
                              void* d_out, int out_size, void* d_ws, size_t ws_size,
                              hipStream_t stream)
{
    const float* x  = (const float*)d_in[0];
    const int*   ei = (const int*)d_in[1];
    int N = in_sizes[0] / F;
    int E = in_sizes[1] / 2;
    const int* src = ei;
    const int* dst = ei + E;

    const float* W1  = (const float*)d_in[2];
    const float* as1 = (const float*)d_in[3];
    const float* ad1 = (const float*)d_in[4];
    const float* b1  = (const float*)d_in[5];
    const float* W2  = (const float*)d_in[6];
    const float* as2 = (const float*)d_in[7];
    const float* ad2 = (const float*)d_in[8];
    const float* b2  = (const float*)d_in[9];
    const float* W3  = (const float*)d_in[10];
    const float* as3 = (const float*)d_in[11];
    const float* ad3 = (const float*)d_in[12];
    const float* b3  = (const float*)d_in[13];
    const float* Wl  = (const float*)d_in[14];
    const float* bl  = (const float*)d_in[15];

    int NBUK = (N + 255) >> 8;            // 391 for N=100000

    float* ws = (float*)d_ws;
    size_t off = 0;
    __half* hA = (__half*)(ws + off); off += (size_t)N * F / 2;
    __half* hB = (__half*)(ws + off); off += (size_t)N * F / 2;
    __half* yA = (__half*)(ws + off); off += (size_t)N * F / 2;
    __half* yB = (__half*)(ws + off); off += (size_t)N * F / 2;
    float* aS = ws + off; off += N;
    float* aD = ws + off; off += N;
    int* cnt = (int*)(ws + off); off += N;
    int* gcount = (int*)(ws + off); off += 512;
    int* csr = (int*)(ws + off); off += (size_t)N * PAD;
    int2* bucketed = (int2*)(ws + off); off += (size_t)NBUK * GBCAP * 2;

    dim3 blk(256);
    int g8 = (N + 7) / 8;
    int TB = (N + 255) / 256;
    int GP = (E + 4095) / 4096;

    // CSR build (bucket partition) + layer-1 MFMA transform, overlapped
    zero512<<<1, blk, 0, stream>>>(gcount);
    build_or_transform<<<GP + TB, blk, 0, stream>>>(src, dst, E, gcount, bucketed,
                                                    x, W1, as1, ad1, hA, aS, aD, N, GP);
    bucket_to_csr<<<NBUK, blk, 0, stream>>>(gcount, bucketed, cnt, csr, N);

    // layer 1 aggregation
    agg_slim<<<g8, blk, 0, stream>>>(cnt, csr, aS, aD, hA, b1, yA, N);
    // layer 2
    mm_mfma<__half, F, false><<<TB, blk, 0, stream>>>(yA, W2, as2, ad2, nullptr,
                                                      hB, nullptr, aS, aD, N);
    agg_slim<<<g8, blk, 0, stream>>>(cnt, csr, aS, aD, hB, b2, yB, N);
    // layer 3
    mm_mfma<__half, F, false><<<TB, blk, 0, stream>>>(yB, W3, as3, ad3, nullptr,
                                                      hA, nullptr, aS, aD, N);
    agg_slim<<<g8, blk, 0, stream>>>(cnt, csr, aS, aD, hA, b3, yA, N);
    // final linear
    mm_mfma<__half, OUTF, true><<<TB, blk, 0, stream>>>(yA, Wl, nullptr, nullptr, bl,
                                                        nullptr, (float*)d_out, nullptr, nullptr, N);
}